// Round 1
// baseline (534.284 us; speedup 1.0000x reference)
//
#include <hip/hip_runtime.h>
#include <math.h>

#define NDIM 4096
#define NNZ_C 110592
#define BATCH 128

typedef unsigned short ushort_t;
typedef __attribute__((ext_vector_type(4))) float f32x4;
typedef __attribute__((ext_vector_type(8))) short s16x8;

// ---------------------------------------------------------------- helpers
__device__ __forceinline__ float selu_f(float x) {
    const float scale = 1.0507009873554804934193349852946f;
    const float alpha = 1.6732632423543772848170429916717f;
    return x > 0.0f ? scale * x : scale * alpha * expm1f(x);
}

__device__ __forceinline__ void gload_lds16(const float* g, char* l) {
    __builtin_amdgcn_global_load_lds(
        (const __attribute__((address_space(1))) unsigned int*)g,
        (__attribute__((address_space(3))) unsigned int*)l, 16, 0, 0);
}

// split fp32 -> (hi,lo) bf16 by truncation: x ~= hi + lo, |err| <= 2^-17 |x|
__device__ __forceinline__ void split_f32(float v, ushort_t& hi, ushort_t& lo) {
    unsigned u = __builtin_bit_cast(unsigned, v);
    hi = (ushort_t)(u >> 16);
    float hf = __builtin_bit_cast(float, u & 0xffff0000u);
    lo = (ushort_t)(__builtin_bit_cast(unsigned, v - hf) >> 16);
}

// ---------------------------------------------------------------- 1) transpose x [128][4096] -> xt [4096][128]
__global__ __launch_bounds__(256) void k_transpose(const float* __restrict__ x,
                                                   float* __restrict__ xt) {
    __shared__ float tile[32][33];
    int bn = blockIdx.x;          // 0..127 (n tiles)
    int bb = blockIdx.y;          // 0..3   (b tiles)
    int tx = threadIdx.x & 31;
    int ty = threadIdx.x >> 5;    // 0..7
#pragma unroll
    for (int i = 0; i < 4; ++i)
        tile[ty + i * 8][tx] = x[(size_t)(bb * 32 + ty + i * 8) * NDIM + bn * 32 + tx];
    __syncthreads();
#pragma unroll
    for (int i = 0; i < 4; ++i)
        xt[(size_t)(bn * 32 + ty + i * 8) * BATCH + bb * 32 + tx] = tile[tx][ty + i * 8];
}

// ---------------------------------------------------------------- 2) COO scatter: yt[r][b] += val * xt[c][b]
__global__ __launch_bounds__(256) void k_spmv(const int* __restrict__ rows,
                                              const int* __restrict__ cols,
                                              const float* __restrict__ vals,
                                              const float* __restrict__ xt,
                                              float* __restrict__ yt) {
    int t = blockIdx.x * 256 + threadIdx.x;
    int e = t >> 5;               // nnz index (32 threads per nnz)
    int q = t & 31;               // batch quad
    float v = vals[e];
    int r = rows[e];
    int c = cols[e];
    f32x4 xv = *(const f32x4*)(xt + (size_t)c * BATCH + q * 4);
    float* yp = yt + (size_t)r * BATCH + q * 4;
    atomicAdd(yp + 0, v * xv[0]);
    atomicAdd(yp + 1, v * xv[1]);
    atomicAdd(yp + 2, v * xv[2]);
    atomicAdd(yp + 3, v * xv[3]);
}

// ---------------------------------------------------------------- 3) x1 = bc + yt*flag, split to hi/lo bf16 in A-frag layout [K/8][128][8]
__global__ __launch_bounds__(256) void k_build_x1(const float* __restrict__ yt,
                                                  const float* __restrict__ bc,
                                                  const float* __restrict__ flag,
                                                  ushort_t* __restrict__ Ahi,
                                                  ushort_t* __restrict__ Alo) {
    int idx = blockIdx.x * 256 + threadIdx.x;   // 65536 total
    int kc = idx >> 7;     // 0..511
    int b  = idx & 127;
    ushort_t h[8], lo[8];
#pragma unroll
    for (int j = 0; j < 8; ++j) {
        int m = kc * 8 + j;
        float v = bc[m] + yt[(size_t)m * BATCH + b] * flag[m];
        split_f32(v, h[j], lo[j]);
    }
    s16x8 hv, lv;
#pragma unroll
    for (int j = 0; j < 8; ++j) { hv[j] = (short)h[j]; lv[j] = (short)lo[j]; }
    *(s16x8*)(Ahi + ((size_t)kc * BATCH + b) * 8) = hv;
    *(s16x8*)(Alo + ((size_t)kc * BATCH + b) * 8) = lv;
}

// ---------------------------------------------------------------- 4) fused GEMM: t[b,n,s] = sum_m W1[s,n,m]*x1[b,m]; out = bc + (sum_s selu(t)*w2)*flag
// grid = 256 blocks (n0 = bid*16), 512 threads = 8 waves; wave w owns b-rows [w*16, w*16+16)
// LDS: 2 bufs x 24 planes x 1KB. Plane P = s*8 + c*2 + p holds, at lane*16,
//      W1[s][n0+(l&15)][m0 + c*32 + (l>>4)*8 + p*4 .. +3]  (exactly the B-frag order)
__global__ __launch_bounds__(512) void k_gemm(const float* __restrict__ W1,
                                              const ushort_t* __restrict__ Ahi,
                                              const ushort_t* __restrict__ Alo,
                                              const float* __restrict__ bc,
                                              const float* __restrict__ flag,
                                              const float* __restrict__ w2,
                                              float* __restrict__ out) {
    __shared__ __align__(16) char lds[2 * 24 * 1024];
    const int tid = threadIdx.x;
    const int w = tid >> 6;
    const int l = tid & 63;
    const int lr = l & 15;
    const int lh = l >> 4;
    const int n0 = blockIdx.x * 16;

    f32x4 acc[3];
#pragma unroll
    for (int s = 0; s < 3; ++s) acc[s] = (f32x4){0.f, 0.f, 0.f, 0.f};

    // 3 staging instructions per wave, plane P = w + i*8
    const float* gbase[3];
    int Ps[3];
#pragma unroll
    for (int i = 0; i < 3; ++i) {
        int P = w + i * 8;
        int s = P >> 3, c = (P >> 1) & 3, p = P & 1;
        gbase[i] = W1 + ((size_t)(s * NDIM + n0 + lr)) * NDIM + c * 32 + lh * 8 + p * 4;
        Ps[i] = P;
    }

    const ushort_t* Abase_hi = Ahi + (size_t)(w * 16 + lr) * 8;  // + kc*1024 elems
    const ushort_t* Abase_lo = Alo + (size_t)(w * 16 + lr) * 8;

    // prologue: stage buf0 (m0 = 0)
#pragma unroll
    for (int i = 0; i < 3; ++i) gload_lds16(gbase[i], lds + Ps[i] * 1024);
    __syncthreads();

    const int KITERS = NDIM / 128;  // 32
    for (int it = 0; it < KITERS; ++it) {
        char* cur = lds + (it & 1) * 24576;
        if (it + 1 < KITERS) {
            char* nxt = lds + ((it + 1) & 1) * 24576;
            size_t m0n = (size_t)(it + 1) * 128;
#pragma unroll
            for (int i = 0; i < 3; ++i) gload_lds16(gbase[i] + m0n, nxt + Ps[i] * 1024);
        }
#pragma unroll
        for (int c = 0; c < 4; ++c) {
            int kc = it * 16 + c * 4 + lh;
            s16x8 ahi = *(const s16x8*)(Abase_hi + (size_t)kc * 1024);
            s16x8 alo = *(const s16x8*)(Abase_lo + (size_t)kc * 1024);
#pragma unroll
            for (int s = 0; s < 3; ++s) {
                f32x4 b0 = *(const f32x4*)(cur + ((s * 4 + c) * 2 + 0) * 1024 + l * 16);
                f32x4 b1 = *(const f32x4*)(cur + ((s * 4 + c) * 2 + 1) * 1024 + l * 16);
                s16x8 bhi, blo;
#pragma unroll
                for (int j = 0; j < 4; ++j) {
                    ushort_t h, lo16;
                    split_f32(b0[j], h, lo16);
                    bhi[j] = (short)h; blo[j] = (short)lo16;
                    split_f32(b1[j], h, lo16);
                    bhi[j + 4] = (short)h; blo[j + 4] = (short)lo16;
                }
                acc[s] = __builtin_amdgcn_mfma_f32_16x16x32_bf16(ahi, bhi, acc[s], 0, 0, 0);
                acc[s] = __builtin_amdgcn_mfma_f32_16x16x32_bf16(ahi, blo, acc[s], 0, 0, 0);
                acc[s] = __builtin_amdgcn_mfma_f32_16x16x32_bf16(alo, bhi, acc[s], 0, 0, 0);
            }
        }
        __syncthreads();
    }

    // epilogue: C/D layout col = l&15 (n), row = (l>>4)*4 + i (b within wave tile)
    int n = n0 + lr;
    float bcv = bc[n], fl = flag[n];
    float w20 = w2[n * 3 + 0], w21 = w2[n * 3 + 1], w22 = w2[n * 3 + 2];
#pragma unroll
    for (int i = 0; i < 4; ++i) {
        int b = w * 16 + lh * 4 + i;
        float sum = selu_f(acc[0][i]) * w20 + selu_f(acc[1][i]) * w21 + selu_f(acc[2][i]) * w22;
        out[(size_t)b * NDIM + n] = bcv + sum * fl;
    }
}

// ---------------------------------------------------------------- launch
extern "C" void kernel_launch(void* const* d_in, const int* in_sizes, int n_in,
                              void* d_out, int out_size, void* d_ws, size_t ws_size,
                              hipStream_t stream) {
    const float* x    = (const float*)d_in[0];
    const float* bc   = (const float*)d_in[1];
    const float* flag = (const float*)d_in[2];
    const int*   rows = (const int*)d_in[3];
    const int*   cols = (const int*)d_in[4];
    const float* vals = (const float*)d_in[5];
    const float* W1   = (const float*)d_in[6];
    const float* w2   = (const float*)d_in[7];
    float* out = (float*)d_out;

    char* ws = (char*)d_ws;
    float*    yt  = (float*)(ws);                       // [4096][128] f32, 2MB
    float*    xt  = (float*)(ws + (2u << 20));          // [4096][128] f32, 2MB
    ushort_t* Ahi = (ushort_t*)(ws + (4u << 20));       // [512][128][8] bf16, 1MB
    ushort_t* Alo = (ushort_t*)(ws + (5u << 20));       // 1MB

    hipMemsetAsync(yt, 0, (size_t)NDIM * BATCH * sizeof(float), stream);
    k_transpose<<<dim3(NDIM / 32, BATCH / 32), 256, 0, stream>>>(x, xt);
    k_spmv<<<(NNZ_C * 32) / 256, 256, 0, stream>>>(rows, cols, vals, xt, yt);
    k_build_x1<<<(512 * BATCH) / 256, 256, 0, stream>>>(yt, bc, flag, Ahi, Alo);
    k_gemm<<<NDIM / 16, 512, 0, stream>>>(W1, Ahi, Alo, bc, flag, w2, out);
}

// Round 2
// 387.848 us; speedup vs baseline: 1.3776x; 1.3776x over previous
//
#include <hip/hip_runtime.h>
#include <math.h>

#define NDIM 4096
#define NNZ_C 110592
#define BATCH 128

typedef unsigned short ushort_t;
typedef __attribute__((ext_vector_type(4))) float f32x4;
typedef __attribute__((ext_vector_type(8))) short s16x8;
typedef __attribute__((ext_vector_type(2))) unsigned uint2v;

// ---------------------------------------------------------------- helpers
__device__ __forceinline__ float selu_f(float x) {
    const float scale = 1.0507009873554804934193349852946f;
    const float alpha = 1.6732632423543772848170429916717f;
    return x > 0.0f ? scale * x : scale * alpha * expm1f(x);
}

__device__ __forceinline__ void gload_lds16(const float* g, char* l) {
    __builtin_amdgcn_global_load_lds(
        (const __attribute__((address_space(1))) unsigned int*)g,
        (__attribute__((address_space(3))) unsigned int*)l, 16, 0, 0);
}

// pack 2 f32 -> 2 bf16 (RTNE), low16 = a, high16 = b
__device__ __forceinline__ unsigned cvt_pk_bf16(float a, float b) {
    unsigned r;
    asm volatile("v_cvt_pk_bf16_f32 %0, %1, %2" : "=v"(r) : "v"(a), "v"(b));
    return r;
}

// ---------------------------------------------------------------- 1) transpose x [128][4096] -> xt [4096][128]
__global__ __launch_bounds__(256) void k_transpose(const float* __restrict__ x,
                                                   float* __restrict__ xt) {
    __shared__ float tile[32][33];
    int bn = blockIdx.x, bb = blockIdx.y;
    int tx = threadIdx.x & 31, ty = threadIdx.x >> 5;
#pragma unroll
    for (int i = 0; i < 4; ++i)
        tile[ty + i * 8][tx] = x[(size_t)(bb * 32 + ty + i * 8) * NDIM + bn * 32 + tx];
    __syncthreads();
#pragma unroll
    for (int i = 0; i < 4; ++i)
        xt[(size_t)(bn * 32 + ty + i * 8) * BATCH + bb * 32 + tx] = tile[tx][ty + i * 8];
}

// ---------------------------------------------------------------- 2) CSR build: histogram, scan, fill
__global__ __launch_bounds__(256) void k_hist(const int* __restrict__ rows, int* __restrict__ count) {
    int e = blockIdx.x * 256 + threadIdx.x;
    atomicAdd(&count[rows[e]], 1);
}

__global__ __launch_bounds__(1024) void k_scan(const int* __restrict__ count,
                                               int* __restrict__ offs, int* __restrict__ cursor) {
    __shared__ int sl[1024];
    int t = threadIdx.x;
    int4 c = *(const int4*)(count + t * 4);
    int s = c.x + c.y + c.z + c.w;
    sl[t] = s;
    __syncthreads();
    int acc = s;
    for (int d = 1; d < 1024; d <<= 1) {
        int v = (t >= d) ? sl[t - d] : 0;
        __syncthreads();
        acc += v;
        sl[t] = acc;
        __syncthreads();
    }
    int excl = acc - s;
    int4 o;
    o.x = excl; o.y = excl + c.x; o.z = o.y + c.y; o.w = o.z + c.z;
    *(int4*)(offs + t * 4) = o;
    *(int4*)(cursor + t * 4) = o;
    if (t == 1023) offs[4096] = excl + s;
}

__global__ __launch_bounds__(256) void k_fill(const int* __restrict__ rows, const int* __restrict__ cols,
                                              const float* __restrict__ vals,
                                              int* __restrict__ cursor, int2* __restrict__ colv) {
    int e = blockIdx.x * 256 + threadIdx.x;
    int r = rows[e];
    int p = atomicAdd(&cursor[r], 1);
    int2 cv;
    cv.x = cols[e];
    cv.y = __float_as_int(vals[e]);
    colv[p] = cv;
}

// ---------------------------------------------------------------- 3) gather spmv + bc/flag + bf16 split -> A-frag layout
// block = one row r (128 threads = batch). Ahi/Alo layout: [(m>>3)*128 + b]*8 + (m&7)
__global__ __launch_bounds__(128) void k_gather(const int2* __restrict__ colv, const int* __restrict__ offs,
                                                const float* __restrict__ xt, const float* __restrict__ bc,
                                                const float* __restrict__ flag,
                                                ushort_t* __restrict__ Ahi, ushort_t* __restrict__ Alo) {
    int r = blockIdx.x;
    int b = threadIdx.x;
    int beg = offs[r], end = offs[r + 1];
    float s0 = 0.f, s1 = 0.f, s2 = 0.f, s3 = 0.f;
    int i = beg;
    for (; i + 4 <= end; i += 4) {
        int2 a0 = colv[i], a1 = colv[i + 1], a2 = colv[i + 2], a3 = colv[i + 3];
        s0 += __int_as_float(a0.y) * xt[(size_t)a0.x * BATCH + b];
        s1 += __int_as_float(a1.y) * xt[(size_t)a1.x * BATCH + b];
        s2 += __int_as_float(a2.y) * xt[(size_t)a2.x * BATCH + b];
        s3 += __int_as_float(a3.y) * xt[(size_t)a3.x * BATCH + b];
    }
    for (; i < end; ++i) {
        int2 a0 = colv[i];
        s0 += __int_as_float(a0.y) * xt[(size_t)a0.x * BATCH + b];
    }
    float v = bc[r] + ((s0 + s1) + (s2 + s3)) * flag[r];
    unsigned h = cvt_pk_bf16(v, v);
    ushort_t hi = (ushort_t)(h & 0xffffu);
    float res = v - __uint_as_float((unsigned)hi << 16);
    unsigned lw = cvt_pk_bf16(res, res);
    size_t base = ((size_t)(r >> 3) * BATCH + b) * 8 + (r & 7);
    Ahi[base] = hi;
    Alo[base] = (ushort_t)(lw & 0xffffu);
}

// ---------------------------------------------------------------- 4) fused GEMM (bf16x3 fp32 emulation)
// grid 256 (n0 = bid*16), 512 thr = 8 waves (wave w = batch rows w*16..+15).
// LDS: f32 stage dbuf 2x24KB @0; bf16 dbuf 2x24KB @49152 (hi 12KB + lo 12KB each).
// f32 layout: row r = s*16+n (48 rows) of 128 f32, linear.
// bf16 layout: plane (s*4+kc) 1KB: byte = plane*1024 + n*64 + kk*2  (kk = k%32).
__global__ __launch_bounds__(512, 1) void k_gemm(const float* __restrict__ W1,
                                                 const ushort_t* __restrict__ Ahi,
                                                 const ushort_t* __restrict__ Alo,
                                                 const float* __restrict__ bc,
                                                 const float* __restrict__ flag,
                                                 const float* __restrict__ w2,
                                                 float* __restrict__ out) {
    __shared__ __align__(16) char lds[98304];
    const int tid = threadIdx.x;
    const int w = tid >> 6, l = tid & 63;
    const int lr = l & 15, lh = l >> 4;
    const int n0 = blockIdx.x * 16;

    f32x4 acc[3] = {};

    // staging: 3 global_load_lds per wave; gload g covers rows 6w+2g, 6w+2g+1 (1KB, 2x512B contiguous)
    const float* gptr[3];
    int ldsoff[3];
#pragma unroll
    for (int g = 0; g < 3; ++g) {
        int r = 6 * w + 2 * g + (l >> 5);
        int s = r >> 4, n = r & 15;
        gptr[g] = W1 + ((size_t)s * NDIM + n0 + n) * NDIM + (l & 31) * 4;
        ldsoff[g] = (6 * w + 2 * g) * 512;
    }

    // split duty: quads Q = tid + q*512 (stride-16B conflict-free b128 reads)
    int dsrc[3], dhi[3];
#pragma unroll
    for (int q = 0; q < 3; ++q) {
        int Q = tid + q * 512;
        int f = Q * 4;
        int s = f >> 11, n = (f >> 7) & 15, mm = f & 127;
        dsrc[q] = Q * 16;
        dhi[q] = ((s * 4 + (mm >> 5)) << 10) + n * 64 + (mm & 31) * 2;
    }

    const ushort_t* Abase_hi = Ahi + (size_t)(w * 16 + lr) * 8;
    const ushort_t* Abase_lo = Alo + (size_t)(w * 16 + lr) * 8;

    // prologue: stage iter 0 into f32 buf0
#pragma unroll
    for (int g = 0; g < 3; ++g) gload_lds16(gptr[g], lds + ldsoff[g]);

    for (int it = 0; it < 32; ++it) {
        const int cur = it & 1;
        char* f32b = lds + cur * 24576;
        char* bfb  = lds + 49152 + cur * 24576;

        asm volatile("s_waitcnt vmcnt(0)" ::: "memory");
        __builtin_amdgcn_s_barrier();
        __builtin_amdgcn_sched_barrier(0);

        // issue next tile's staging early (other f32 buffer; window = full iter)
        if (it + 1 < 32) {
            char* f32n = lds + (1 - cur) * 24576;
            size_t moff = (size_t)(it + 1) * 128;
#pragma unroll
            for (int g = 0; g < 3; ++g) gload_lds16(gptr[g] + moff, f32n + ldsoff[g]);
        }

        // shared split phase: 12 f32 per thread -> bf16 hi/lo planes
#pragma unroll
        for (int q = 0; q < 3; ++q) {
            f32x4 v = *(const f32x4*)(f32b + dsrc[q]);
            unsigned h01 = cvt_pk_bf16(v[0], v[1]);
            unsigned h23 = cvt_pk_bf16(v[2], v[3]);
            float r0 = v[0] - __uint_as_float(h01 << 16);
            float r1 = v[1] - __uint_as_float(h01 & 0xffff0000u);
            float r2 = v[2] - __uint_as_float(h23 << 16);
            float r3 = v[3] - __uint_as_float(h23 & 0xffff0000u);
            unsigned l01 = cvt_pk_bf16(r0, r1);
            unsigned l23 = cvt_pk_bf16(r2, r3);
            *(uint2v*)(bfb + dhi[q]) = (uint2v){h01, h23};
            *(uint2v*)(bfb + 12288 + dhi[q]) = (uint2v){l01, l23};
        }

        asm volatile("s_waitcnt lgkmcnt(0)" ::: "memory");
        __builtin_amdgcn_s_barrier();
        __builtin_amdgcn_sched_barrier(0);

        // MFMA phase: 36 mfma per thread-iter
#pragma unroll
        for (int c = 0; c < 4; ++c) {
            int kcg = it * 16 + c * 4 + lh;
            s16x8 ahi = *(const s16x8*)(Abase_hi + (size_t)kcg * (BATCH * 8));
            s16x8 alo = *(const s16x8*)(Abase_lo + (size_t)kcg * (BATCH * 8));
#pragma unroll
            for (int s = 0; s < 3; ++s) {
                int off = ((s * 4 + c) << 10) + lr * 64 + lh * 16;
                s16x8 bhi = *(const s16x8*)(bfb + off);
                s16x8 blo = *(const s16x8*)(bfb + 12288 + off);
                acc[s] = __builtin_amdgcn_mfma_f32_16x16x32_bf16(ahi, bhi, acc[s], 0, 0, 0);
                acc[s] = __builtin_amdgcn_mfma_f32_16x16x32_bf16(ahi, blo, acc[s], 0, 0, 0);
                acc[s] = __builtin_amdgcn_mfma_f32_16x16x32_bf16(alo, bhi, acc[s], 0, 0, 0);
            }
        }
    }

    // epilogue: C/D col = l&15 (n), row = lh*4+i (batch within wave tile)
    int n = n0 + lr;
    float bcv = bc[n], fl = flag[n];
    float w20 = w2[n * 3 + 0], w21 = w2[n * 3 + 1], w22 = w2[n * 3 + 2];
#pragma unroll
    for (int i = 0; i < 4; ++i) {
        int b = w * 16 + lh * 4 + i;
        float sum = selu_f(acc[0][i]) * w20 + selu_f(acc[1][i]) * w21 + selu_f(acc[2][i]) * w22;
        out[(size_t)b * NDIM + n] = bcv + sum * fl;
    }
}

// ---------------------------------------------------------------- launch
extern "C" void kernel_launch(void* const* d_in, const int* in_sizes, int n_in,
                              void* d_out, int out_size, void* d_ws, size_t ws_size,
                              hipStream_t stream) {
    const float* x    = (const float*)d_in[0];
    const float* bc   = (const float*)d_in[1];
    const float* flag = (const float*)d_in[2];
    const int*   rows = (const int*)d_in[3];
    const int*   cols = (const int*)d_in[4];
    const float* vals = (const float*)d_in[5];
    const float* W1   = (const float*)d_in[6];
    const float* w2   = (const float*)d_in[7];
    float* out = (float*)d_out;

    char* ws = (char*)d_ws;
    float*    xt     = (float*)(ws);                         // 2 MB
    ushort_t* Ahi    = (ushort_t*)(ws + (2u << 20));         // 1 MB
    ushort_t* Alo    = (ushort_t*)(ws + (3u << 20));         // 1 MB
    int*      count  = (int*)(ws + (4u << 20));              // 16 KB
    int*      cursor = count + 4096;                         // 16 KB
    int*      offs   = cursor + 4096;                        // 16.4 KB
    int2*     colv   = (int2*)(ws + (4u << 20) + 65536);     // 864 KB

    hipMemsetAsync(count, 0, 4096 * sizeof(int), stream);
    k_transpose<<<dim3(NDIM / 32, BATCH / 32), 256, 0, stream>>>(x, xt);
    k_hist<<<NNZ_C / 256, 256, 0, stream>>>(rows, count);
    k_scan<<<1, 1024, 0, stream>>>(count, offs, cursor);
    k_fill<<<NNZ_C / 256, 256, 0, stream>>>(rows, cols, vals, cursor, colv);
    k_gather<<<NDIM, 128, 0, stream>>>(colv, offs, xt, bc, flag, Ahi, Alo);
    k_gemm<<<NDIM / 16, 512, 0, stream>>>(W1, Ahi, Alo, bc, flag, w2, out);
}